// Round 3
// baseline (120.857 us; speedup 1.0000x reference)
//
#include <hip/hip_runtime.h>

// Network24: out = sigmoid( m0*h0 + m1*h1 + (m2*h0)*(m3*h1) + bias3 )
//   h_j = sigmoid( tw[j][0]*x0^p[j][0] + tw[j][1]*x1^p[j][1] + b_j )
// Powers are 1.0 at runtime; uniform branch keeps the general case correct.
//
// Memory-bound: 64 MB read (x) + 32 MB write (out) per call.
// 8 rows/thread: 4x float4 loads in flight per thread (MLP), 2x NT vector stores.

// Native clang vector type: __builtin_nontemporal_store requires a pointer to
// scalar or vector-of-scalar, which HIP_vector_type (float4) is not.
typedef float vfloat4 __attribute__((ext_vector_type(4)));

__device__ __forceinline__ float pw(float x, float p) {
    return (p == 1.0f) ? x : __powf(x, p);
}
__device__ __forceinline__ float sigmoidf(float z) {
    return 1.0f / (1.0f + __expf(-z));
}

__global__ __launch_bounds__(256) void net24_kernel(
    const float* __restrict__ x,        // (n, 2) row-major
    float* __restrict__ out,            // (n,)
    const float* __restrict__ fc1_tw,   // (2,2,3) -> use [j,k,0] = j*6+k*3
    const float* __restrict__ fc1_power,// (2,2)
    const float* __restrict__ fc1_bias, // (2,)
    const float* __restrict__ m4_tw,    // (4,3) -> use [i,0] = i*3
    const float* __restrict__ m4_power, // (4,)
    const float* __restrict__ m4_bias3, // (1,)
    int n)                              // rows
{
    // Uniform addresses -> wave-uniform loads, broadcast to all lanes.
    const float tw00 = fc1_tw[0], tw01 = fc1_tw[3], tw10 = fc1_tw[6], tw11 = fc1_tw[9];
    const float p00 = fc1_power[0], p01 = fc1_power[1], p10 = fc1_power[2], p11 = fc1_power[3];
    const float b0 = fc1_bias[0], b1 = fc1_bias[1];
    const float m0 = m4_tw[0], m1 = m4_tw[3], m2 = m4_tw[6], m3 = m4_tw[9];
    const float q0 = m4_power[0], q1 = m4_power[1], q2 = m4_power[2], q3 = m4_power[3];
    const float bias3 = m4_bias3[0];

    auto eval_row = [&](float x0, float x1) -> float {
        float h0 = sigmoidf(fmaf(tw00, pw(x0, p00), fmaf(tw01, pw(x1, p01), b0)));
        float h1 = sigmoidf(fmaf(tw10, pw(x0, p10), fmaf(tw11, pw(x1, p11), b1)));
        float s  = fmaf(m0, pw(h0, q0), fmaf(m1, pw(h1, q1), bias3));
        s = fmaf(m2 * pw(h0, q2), m3 * pw(h1, q3), s);
        return sigmoidf(s);
    };

    const int i = blockIdx.x * blockDim.x + threadIdx.x;  // group of 8 rows
    const long long row0 = (long long)i * 8;
    if (row0 >= n) return;

    if (row0 + 8 <= n) {
        // 4x vfloat4 loads issued back-to-back (16 floats = 8 rows of x).
        const vfloat4* xv = (const vfloat4*)(x + row0 * 2);
        vfloat4 a = xv[0];
        vfloat4 b = xv[1];
        vfloat4 c = xv[2];
        vfloat4 d = xv[3];
        vfloat4 r0, r1;
        r0.x = eval_row(a.x, a.y);
        r0.y = eval_row(a.z, a.w);
        r0.z = eval_row(b.x, b.y);
        r0.w = eval_row(b.z, b.w);
        r1.x = eval_row(c.x, c.y);
        r1.y = eval_row(c.z, c.w);
        r1.z = eval_row(d.x, d.y);
        r1.w = eval_row(d.z, d.w);
        // Streaming output: no reuse, keep L2/L3 for x.
        __builtin_nontemporal_store(r0, (vfloat4*)(out + row0));
        __builtin_nontemporal_store(r1, (vfloat4*)(out + row0 + 4));
    } else {
        for (long long r = row0; r < n; ++r) {
            out[r] = eval_row(x[r * 2], x[r * 2 + 1]);
        }
    }
}

extern "C" void kernel_launch(void* const* d_in, const int* in_sizes, int n_in,
                              void* d_out, int out_size, void* d_ws, size_t ws_size,
                              hipStream_t stream) {
    const float* x         = (const float*)d_in[0];
    const float* fc1_tw    = (const float*)d_in[1];
    const float* fc1_power = (const float*)d_in[2];
    const float* fc1_bias  = (const float*)d_in[3];
    const float* m4_tw     = (const float*)d_in[4];
    const float* m4_power  = (const float*)d_in[5];
    const float* m4_bias3  = (const float*)d_in[6];
    float* out = (float*)d_out;

    const int n = out_size;               // B rows, one output each
    const int n8 = (n + 7) / 8;           // rows handled 8-per-thread
    const int block = 256;
    const int grid = (n8 + block - 1) / block;

    net24_kernel<<<grid, block, 0, stream>>>(x, out, fc1_tw, fc1_power, fc1_bias,
                                             m4_tw, m4_power, m4_bias3, n);
}

// Round 4
// 110.562 us; speedup vs baseline: 1.0931x; 1.0931x over previous
//
#include <hip/hip_runtime.h>

// Network24: out = sigmoid( m0*h0 + m1*h1 + (m2*h0)*(m3*h1) + bias3 )
//   h_j = sigmoid( tw[j][0]*x0^p[j][0] + tw[j][1]*x1^p[j][1] + b_j )
// Powers are 1.0 at runtime; uniform branch keeps the general case correct.
//
// Memory-bound: ~67 MB read (x) + ~34 MB write (out) per call.
// Wave-contiguous layout: each wave owns 256 consecutive rows (128 float4s of x).
//   load k: lane l reads float4 [k*64 + l]  -> unit stride, 1 KB per instruction.
//   Each float4 holds exactly 2 rows, so no cross-lane shuffle is needed.
//   Stores: two unit-stride float2s per lane.
// (R2 post-mortem: R rows/thread with thread-contiguous float4s gives lane
//  stride 8R bytes -> uncoalesced; 64 B stride cost ~10 us. This fixes that.)

typedef float vfloat4 __attribute__((ext_vector_type(4)));
typedef float vfloat2 __attribute__((ext_vector_type(2)));

__device__ __forceinline__ float pw(float x, float p) {
    return (p == 1.0f) ? x : __powf(x, p);
}
__device__ __forceinline__ float sigmoidf(float z) {
    return 1.0f / (1.0f + __expf(-z));
}

__global__ __launch_bounds__(256) void net24_kernel(
    const float* __restrict__ x,        // (n, 2) row-major
    float* __restrict__ out,            // (n,)
    const float* __restrict__ fc1_tw,   // (2,2,3) -> use [j,k,0] = j*6+k*3
    const float* __restrict__ fc1_power,// (2,2)
    const float* __restrict__ fc1_bias, // (2,)
    const float* __restrict__ m4_tw,    // (4,3) -> use [i,0] = i*3
    const float* __restrict__ m4_power, // (4,)
    const float* __restrict__ m4_bias3, // (1,)
    int n)                              // rows
{
    // Uniform addresses -> wave-uniform loads, broadcast to all lanes.
    const float tw00 = fc1_tw[0], tw01 = fc1_tw[3], tw10 = fc1_tw[6], tw11 = fc1_tw[9];
    const float p00 = fc1_power[0], p01 = fc1_power[1], p10 = fc1_power[2], p11 = fc1_power[3];
    const float b0 = fc1_bias[0], b1 = fc1_bias[1];
    const float m0 = m4_tw[0], m1 = m4_tw[3], m2 = m4_tw[6], m3 = m4_tw[9];
    const float q0 = m4_power[0], q1 = m4_power[1], q2 = m4_power[2], q3 = m4_power[3];
    const float bias3 = m4_bias3[0];

    auto eval_row = [&](float x0, float x1) -> float {
        float h0 = sigmoidf(fmaf(tw00, pw(x0, p00), fmaf(tw01, pw(x1, p01), b0)));
        float h1 = sigmoidf(fmaf(tw10, pw(x0, p10), fmaf(tw11, pw(x1, p11), b1)));
        float s  = fmaf(m0, pw(h0, q0), fmaf(m1, pw(h1, q1), bias3));
        s = fmaf(m2 * pw(h0, q2), m3 * pw(h1, q3), s);
        return sigmoidf(s);
    };

    const int gid  = blockIdx.x * blockDim.x + threadIdx.x;
    const int wave = gid >> 6;
    const int lane = gid & 63;
    const long long rowbase = (long long)wave * 256;   // this wave's 256 rows
    if (rowbase >= n) return;

    if (rowbase + 256 <= n) {
        const vfloat4* xv = (const vfloat4*)(x + rowbase * 2);  // 128 float4s
        vfloat4 a = xv[lane];        // rows rowbase + 2*lane, +2*lane+1
        vfloat4 b = xv[64 + lane];   // rows rowbase + 128 + 2*lane, ...+1
        vfloat2 ra, rb;
        ra.x = eval_row(a.x, a.y);
        ra.y = eval_row(a.z, a.w);
        rb.x = eval_row(b.x, b.y);
        rb.y = eval_row(b.z, b.w);
        *(vfloat2*)(out + rowbase + 2 * lane)       = ra;   // unit stride 8 B
        *(vfloat2*)(out + rowbase + 128 + 2 * lane) = rb;   // unit stride 8 B
    } else {
        // Tail (not hit for n = 2^23): lane-strided scalar over the region.
        for (long long r = rowbase + lane; r < n; r += 64) {
            out[r] = eval_row(x[r * 2], x[r * 2 + 1]);
        }
    }
}

extern "C" void kernel_launch(void* const* d_in, const int* in_sizes, int n_in,
                              void* d_out, int out_size, void* d_ws, size_t ws_size,
                              hipStream_t stream) {
    const float* x         = (const float*)d_in[0];
    const float* fc1_tw    = (const float*)d_in[1];
    const float* fc1_power = (const float*)d_in[2];
    const float* fc1_bias  = (const float*)d_in[3];
    const float* m4_tw     = (const float*)d_in[4];
    const float* m4_power  = (const float*)d_in[5];
    const float* m4_bias3  = (const float*)d_in[6];
    float* out = (float*)d_out;

    const int n = out_size;                     // B rows, one output each
    const long long waves = ((long long)n + 255) / 256;   // 256 rows per wave
    const long long threads = waves * 64;
    const int block = 256;
    const long long grid = (threads + block - 1) / block;

    net24_kernel<<<(int)grid, block, 0, stream>>>(x, out, fc1_tw, fc1_power, fc1_bias,
                                                  m4_tw, m4_power, m4_bias3, n);
}

// Round 5
// 107.597 us; speedup vs baseline: 1.1232x; 1.0276x over previous
//
#include <hip/hip_runtime.h>

// Network24: out = sigmoid( m0*h0 + m1*h1 + (m2*h0)*(m3*h1) + bias3 )
//   h_j = sigmoid( tw[j][0]*x0 + tw[j][1]*x1 + b_j )        (powers == 1.0)
//
// R4 post-mortem: kernel was VALU-issue-bound (~1070 VALU cy/wave), not
// memory-bound. Causes: IEEE div sequence for 1/(1+e) (~10 ops each, x12/lane)
// and per-lane-predicated __powf fallbacks (~8/row computed+discarded).
// Fix: wave-uniform "all powers == 1" branch + raw v_exp/v_rcp sigmoid.
//
// Memory: ~67 MB HBM read (x, half L3-absorbed) + ~34 MB write -> ~14-16 us floor.

typedef float vfloat4 __attribute__((ext_vector_type(4)));
typedef float vfloat2 __attribute__((ext_vector_type(2)));

__device__ __forceinline__ float sigmoid_fast(float z) {
    // sigmoid(z) = 1 / (1 + exp(-z));  exp(-z) = exp2(-z*log2(e))
    float t = __expf(-z);                      // v_mul + v_exp_f32
    return __builtin_amdgcn_rcpf(1.0f + t);    // v_add + v_rcp_f32 (~1 ulp)
}
__device__ __forceinline__ float sigmoid_exact(float z) {
    return 1.0f / (1.0f + expf(-z));
}
__device__ __forceinline__ float pw(float x, float p) {
    return (p == 1.0f) ? x : __powf(x, p);
}

__global__ __launch_bounds__(256) void net24_kernel(
    const float* __restrict__ x,        // (n, 2) row-major
    float* __restrict__ out,            // (n,)
    const float* __restrict__ fc1_tw,   // (2,2,3) -> use [j,k,0] = j*6+k*3
    const float* __restrict__ fc1_power,// (2,2)
    const float* __restrict__ fc1_bias, // (2,)
    const float* __restrict__ m4_tw,    // (4,3) -> use [i,0] = i*3
    const float* __restrict__ m4_power, // (4,)
    const float* __restrict__ m4_bias3, // (1,)
    int n)                              // rows
{
    // Uniform addresses -> scalar loads, broadcast; branch below is s_cbranch.
    const float tw00 = fc1_tw[0], tw01 = fc1_tw[3], tw10 = fc1_tw[6], tw11 = fc1_tw[9];
    const float p00 = fc1_power[0], p01 = fc1_power[1], p10 = fc1_power[2], p11 = fc1_power[3];
    const float b0 = fc1_bias[0], b1 = fc1_bias[1];
    const float m0 = m4_tw[0], m1 = m4_tw[3], m2 = m4_tw[6], m3 = m4_tw[9];
    const float q0 = m4_power[0], q1 = m4_power[1], q2 = m4_power[2], q3 = m4_power[3];
    const float bias3 = m4_bias3[0];

    const bool all_pow1 = (p00 == 1.0f) & (p01 == 1.0f) & (p10 == 1.0f) & (p11 == 1.0f) &
                          (q0 == 1.0f) & (q1 == 1.0f) & (q2 == 1.0f) & (q3 == 1.0f);

    auto eval_fast = [&](float x0, float x1) -> float {
        float h0 = sigmoid_fast(fmaf(tw00, x0, fmaf(tw01, x1, b0)));
        float h1 = sigmoid_fast(fmaf(tw10, x0, fmaf(tw11, x1, b1)));
        float s  = fmaf(m0, h0, fmaf(m1, h1, bias3));
        s = fmaf(m2 * h0, m3 * h1, s);
        return sigmoid_fast(s);
    };
    auto eval_gen = [&](float x0, float x1) -> float {
        float h0 = sigmoid_exact(fmaf(tw00, pw(x0, p00), fmaf(tw01, pw(x1, p01), b0)));
        float h1 = sigmoid_exact(fmaf(tw10, pw(x0, p10), fmaf(tw11, pw(x1, p11), b1)));
        float s  = fmaf(m0, pw(h0, q0), fmaf(m1, pw(h1, q1), bias3));
        s = fmaf(m2 * pw(h0, q2), m3 * pw(h1, q3), s);
        return sigmoid_exact(s);
    };

    const int gid  = blockIdx.x * blockDim.x + threadIdx.x;
    const int wave = gid >> 6;
    const int lane = gid & 63;
    const long long rowbase = (long long)wave * 256;   // this wave's 256 rows
    if (rowbase >= n) return;

    if (all_pow1 && rowbase + 256 <= n) {
        // Unit-stride: lane l reads float4 [k*64+l]; each float4 = 2 rows.
        const vfloat4* xv = (const vfloat4*)(x + rowbase * 2);  // 128 float4s
        vfloat4 a = xv[lane];
        vfloat4 b = xv[64 + lane];
        vfloat2 ra, rb;
        ra.x = eval_fast(a.x, a.y);
        ra.y = eval_fast(a.z, a.w);
        rb.x = eval_fast(b.x, b.y);
        rb.y = eval_fast(b.z, b.w);
        *(vfloat2*)(out + rowbase + 2 * lane)       = ra;
        *(vfloat2*)(out + rowbase + 128 + 2 * lane) = rb;
    } else {
        // Generic / tail path (never hit in this benchmark's fast case).
        for (long long r = rowbase + lane; r < rowbase + 256 && r < n; r += 64) {
            out[r] = eval_gen(x[r * 2], x[r * 2 + 1]);
        }
    }
}

extern "C" void kernel_launch(void* const* d_in, const int* in_sizes, int n_in,
                              void* d_out, int out_size, void* d_ws, size_t ws_size,
                              hipStream_t stream) {
    const float* x         = (const float*)d_in[0];
    const float* fc1_tw    = (const float*)d_in[1];
    const float* fc1_power = (const float*)d_in[2];
    const float* fc1_bias  = (const float*)d_in[3];
    const float* m4_tw     = (const float*)d_in[4];
    const float* m4_power  = (const float*)d_in[5];
    const float* m4_bias3  = (const float*)d_in[6];
    float* out = (float*)d_out;

    const int n = out_size;                               // B rows
    const long long waves = ((long long)n + 255) / 256;   // 256 rows per wave
    const long long threads = waves * 64;
    const int block = 256;
    const long long grid = (threads + block - 1) / block;

    net24_kernel<<<(int)grid, block, 0, stream>>>(x, out, fc1_tw, fc1_power, fc1_bias,
                                                  m4_tw, m4_power, m4_bias3, n);
}